// Round 10
// baseline (343.101 us; speedup 1.0000x reference)
//
#include <hip/hip_runtime.h>
#include <hip/hip_bf16.h>

// Problem constants (fixed by the reference)
constexpr int B  = 4;
constexpr int N  = 2048;
constexpr int D  = 1024;
constexpr int H  = 16;
constexpr int HD = 64;            // head dim
constexpr int M  = B * N;         // 8192 rows
constexpr int K3 = 3 * D;         // 3072

typedef __attribute__((ext_vector_type(8))) short  short8v;  // 8 bf16 in 4 VGPRs
typedef __attribute__((ext_vector_type(4))) float  f32x4;
typedef __attribute__((ext_vector_type(4))) unsigned short us4;

__device__ inline unsigned short f2bf(float f) {   // fp32 -> bf16 bits, RNE
    union { float f; unsigned u; } x{f};
    unsigned r = x.u + 0x7fffu + ((x.u >> 16) & 1u);
    return (unsigned short)(r >> 16);
}

__device__ __forceinline__ void gload_lds16(const unsigned short* g, unsigned short* l) {
    __builtin_amdgcn_global_load_lds(
        (const __attribute__((address_space(1))) void*)g,
        (__attribute__((address_space(3))) void*)l, 16, 0, 0);
}

__device__ __forceinline__ float max3f(float a, float b, float c) {
    return fmaxf(fmaxf(a, b), c);    // clang fuses to v_max3_f32
}

// ---------------------------------------------------------------------------
// fp32 -> bf16 elementwise (8 elems/thread)
// ---------------------------------------------------------------------------
__global__ __launch_bounds__(256)
void cvt_bf16(const float* __restrict__ in, unsigned short* __restrict__ outp, int n8) {
    int i = blockIdx.x * 256 + threadIdx.x;
    if (i >= n8) return;
    f32x4 a = *(const f32x4*)(in + (size_t)i * 8);
    f32x4 b = *(const f32x4*)(in + (size_t)i * 8 + 4);
    short8v v;
    #pragma unroll
    for (int j = 0; j < 4; ++j) { v[j] = (short)f2bf(a[j]); v[4 + j] = (short)f2bf(b[j]); }
    *(short8v*)(outp + (size_t)i * 8) = v;
}

// ---------------------------------------------------------------------------
// W [Kd][Nd] fp32  ->  Wt [Nd][Kd] bf16   (64x64 tiles via LDS)
// ---------------------------------------------------------------------------
__global__ __launch_bounds__(256)
void transpose_w(const float* __restrict__ W, unsigned short* __restrict__ Wt,
                 int Kd, int Nd) {
    __shared__ unsigned short t[64][68];
    const int k0 = blockIdx.y * 64, n0 = blockIdx.x * 64;
    const int tid = threadIdx.x;
    #pragma unroll
    for (int i = 0; i < 4; ++i) {
        int k = (tid >> 4) + 16 * i, nn = (tid & 15) * 4;
        f32x4 v = *(const f32x4*)(W + (size_t)(k0 + k) * Nd + n0 + nn);
        #pragma unroll
        for (int j = 0; j < 4; ++j) t[k][nn + j] = f2bf(v[j]);
    }
    __syncthreads();
    #pragma unroll
    for (int i = 0; i < 4; ++i) {
        int n = (tid >> 4) + 16 * i, kk = (tid & 15) * 4;
        us4 v = { t[kk][n], t[kk + 1][n], t[kk + 2][n], t[kk + 3][n] };
        *(us4*)(Wt + (size_t)(n0 + n) * Kd + k0 + kk) = v;
    }
}

// ---------------------------------------------------------------------------
// bf16 MFMA GEMM (m97 structure): C[Md][Nd] = A[Md][Kd] @ Bt[Nd][Kd]^T (+bias)
// 128x128 tile, BK=64, 256 thr = 4 waves (2x2), wave = 64x64 quadrant.
// ---------------------------------------------------------------------------
template <bool BIAS, typename OutT>
__global__ __launch_bounds__(256)
void gemm_bf16(const unsigned short* __restrict__ A,   // [Md][Kd]
               const unsigned short* __restrict__ Bt,  // [Nd][Kd]
               OutT* __restrict__ C, const float* __restrict__ bias,
               int Md, int Nd, int Kd) {
    __shared__ unsigned short As[128 * 64];
    __shared__ unsigned short Bs[128 * 64];

    const int tid  = threadIdx.x;
    const int lane = tid & 63;
    const int w    = tid >> 6;
    const int lr   = lane & 15;
    const int lg   = lane >> 4;
    const int wm   = w >> 1, wn = w & 1;
    const int row0 = blockIdx.y * 128;
    const int col0 = blockIdx.x * 128;

    f32x4 acc[4][4] = {};   // [mi][ni]

    for (int k0 = 0; k0 < Kd; k0 += 64) {
        #pragma unroll
        for (int it = 0; it < 4; ++it) {
            const int c    = (it * 4 + w) * 64 + lane;   // chunk 0..1023
            const int row  = c >> 3, slot = c & 7;
            const int gs   = (slot ^ (row & 7)) * 8;     // pre-swizzled source
            gload_lds16(A  + (size_t)(row0 + row) * Kd + k0 + gs, As + c * 8);
            gload_lds16(Bt + (size_t)(col0 + row) * Kd + k0 + gs, Bs + c * 8);
        }
        asm volatile("s_waitcnt vmcnt(0)" ::: "memory");
        __syncthreads();

        short8v af[4][2], bfr[4][2];
        #pragma unroll
        for (int mi = 0; mi < 4; ++mi) {
            const int row = wm * 64 + mi * 16 + lr;
            #pragma unroll
            for (int kk = 0; kk < 2; ++kk)
                af[mi][kk] = *(const short8v*)(As + row * 64 + (((kk * 4 + lg) ^ (row & 7)) * 8));
        }
        #pragma unroll
        for (int ni = 0; ni < 4; ++ni) {
            const int col = wn * 64 + ni * 16 + lr;
            #pragma unroll
            for (int kk = 0; kk < 2; ++kk)
                bfr[ni][kk] = *(const short8v*)(Bs + col * 64 + (((kk * 4 + lg) ^ (col & 7)) * 8));
        }

        #pragma unroll
        for (int kk = 0; kk < 2; ++kk)
            #pragma unroll
            for (int mi = 0; mi < 4; ++mi)
                #pragma unroll
                for (int ni = 0; ni < 4; ++ni)
                    acc[mi][ni] = __builtin_amdgcn_mfma_f32_16x16x32_bf16(
                        af[mi][kk], bfr[ni][kk], acc[mi][ni], 0, 0, 0);

        __syncthreads();
    }

    #pragma unroll
    for (int mi = 0; mi < 4; ++mi) {
        #pragma unroll
        for (int r = 0; r < 4; ++r) {
            const size_t row = row0 + wm * 64 + mi * 16 + 4 * lg + r;
            #pragma unroll
            for (int ni = 0; ni < 4; ++ni) {
                const int col = col0 + wn * 64 + ni * 16 + lr;
                float v = acc[mi][ni][r];
                if constexpr (BIAS) v += bias[col];
                if constexpr (sizeof(OutT) == 2)
                    C[row * (size_t)Nd + col] = (OutT)f2bf(v);
                else
                    C[row * (size_t)Nd + col] = (OutT)v;
            }
        }
    }
}

// ---------------------------------------------------------------------------
// V transpose: qkv_bf V-section [b,n, 2D + h*64 + d] -> Vt[bh][d][n]  (bf16)
// ---------------------------------------------------------------------------
__global__ __launch_bounds__(256)
void transposeV(const unsigned short* __restrict__ qkvb, unsigned short* __restrict__ Vt) {
    __shared__ unsigned short t[64][68];
    const int bh = blockIdx.y, b = bh >> 4, h = bh & 15;
    const int n0 = blockIdx.x * 64;
    const int tid = threadIdx.x;

    #pragma unroll
    for (int i = 0; i < 4; ++i) {
        int key = (tid >> 4) + 16 * i, d0 = (tid & 15) * 4;
        us4 v = *(const us4*)(qkvb + (size_t)(b * N + n0 + key) * K3 + 2 * D + h * 64 + d0);
        *(us4*)&t[key][d0] = v;
    }
    __syncthreads();
    #pragma unroll
    for (int i = 0; i < 4; ++i) {
        int d = (tid >> 4) + 16 * i, k0 = (tid & 15) * 4;
        us4 v = { t[k0][d], t[k0 + 1][d], t[k0 + 2][d], t[k0 + 3][d] };
        *(us4*)(Vt + ((size_t)bh * 64 + d) * N + n0 + k0) = v;
    }
}

// ---------------------------------------------------------------------------
// MFMA bf16 flash attention, swapped QK^T + 2-phase double-buffered pipeline.
// Grid (N/64, B*H), 256 thr = 4 waves; each wave owns 16 q-rows.
// Per tile: STAGE(next tile, buf^1) -> compute buf -> vmcnt(0)+s_barrier.
// global_load_lds has no VGPR result, so prefetch stays in flight across the
// compute phase; the only drain is our end-of-tile vmcnt(0). Softmax in exp2
// domain (scale folded); max via v_max3 chain; setprio(1) around MFMA.
// ---------------------------------------------------------------------------
__global__ __launch_bounds__(256)
void attn_mfma(const unsigned short* __restrict__ qkvb,
               const unsigned short* __restrict__ Vt,
               unsigned short* __restrict__ out) {
    __shared__ unsigned short K_lds[2][64 * 64];  // [key][d] swizzled
    __shared__ unsigned short V_lds[2][64 * 64];  // [d][key] swizzled
    __shared__ unsigned short P_lds[4 * 16 * 64]; // per-wave [q][key] swizzled

    const int tid  = threadIdx.x;
    const int lane = tid & 63;
    const int w    = tid >> 6;
    const int lr   = lane & 15;
    const int lg   = lane >> 4;
    const int bh   = blockIdx.y, b = bh >> 4, h = bh & 15;
    const int q0   = blockIdx.x * 64;

    // Q fragments (B-operand: col=lr=q-row, k=8*lg+e), 2 k-steps over d=64
    short8v qa[2];
    {
        const unsigned short* qrow =
            qkvb + (size_t)(b * N + q0 + w * 16 + lr) * K3 + h * 64 + lg * 8;
        qa[0] = *(const short8v*)(qrow);
        qa[1] = *(const short8v*)(qrow + 32);
    }

    f32x4 oacc[4] = {};
    float mrow = -1e30f;   // running max for q-row lr (per lane)
    float lsum = 0.f;      // per-lane partial sum for q-row lr
    constexpr float CE = 0.125f * 1.44269504089f;   // scale * log2(e)

    const unsigned short* kbase  = qkvb + (size_t)b * N * K3 + D + h * 64;
    const unsigned short* vtbase = Vt + (size_t)bh * 64 * N;

    const int crow = tid >> 3, cslot = tid & 7;           // staging coords (i=0)
    const int gs0  = (cslot ^ (crow & 7)) * 8;
    const int crow1 = (tid + 256) >> 3;                   // i=1
    const int gs1  = (cslot ^ (crow1 & 7)) * 8;

    // prologue: stage tile 0 into buf 0
    {
        gload_lds16(kbase  + (size_t)crow  * K3 + gs0, &K_lds[0][tid * 8]);
        gload_lds16(vtbase + (size_t)crow  * N  + gs0, &V_lds[0][tid * 8]);
        gload_lds16(kbase  + (size_t)crow1 * K3 + gs1, &K_lds[0][(tid + 256) * 8]);
        gload_lds16(vtbase + (size_t)crow1 * N  + gs1, &V_lds[0][(tid + 256) * 8]);
    }
    asm volatile("s_waitcnt vmcnt(0)\n\ts_barrier" ::: "memory");

    int cur = 0;
    for (int t = 0; t < N / 64; ++t) {
        // ---- issue next tile's loads into buf^1 (no wait) ----
        if (t < N / 64 - 1) {
            const int kt1 = (t + 1) * 64;
            unsigned short* kd = (unsigned short*)&K_lds[cur ^ 1][0];
            unsigned short* vd = (unsigned short*)&V_lds[cur ^ 1][0];
            gload_lds16(kbase  + (size_t)(kt1 + crow)  * K3 + gs0, kd + tid * 8);
            gload_lds16(vtbase + (size_t)crow  * N + kt1 + gs0,    vd + tid * 8);
            gload_lds16(kbase  + (size_t)(kt1 + crow1) * K3 + gs1, kd + (tid + 256) * 8);
            gload_lds16(vtbase + (size_t)crow1 * N + kt1 + gs1,    vd + (tid + 256) * 8);
        }

        const unsigned short* Kc = &K_lds[cur][0];
        const unsigned short* Vc = &V_lds[cur][0];

        // ---- S^T = K @ Q^T : sacc[sj][r] = S[key=16sj+4lg+r][q=lr] ----
        f32x4 sacc[4] = {};
        __builtin_amdgcn_s_setprio(1);
        #pragma unroll
        for (int sj = 0; sj < 4; ++sj) {
            const int key = 16 * sj + lr;
            #pragma unroll
            for (int ks = 0; ks < 2; ++ks) {
                short8v kb = *(const short8v*)(Kc + key * 64 +
                                               (((4 * ks + lg) ^ (key & 7)) * 8));
                sacc[sj] = __builtin_amdgcn_mfma_f32_16x16x32_bf16(kb, qa[ks], sacc[sj], 0, 0, 0);
            }
        }
        __builtin_amdgcn_s_setprio(0);

        // ---- row-local online softmax (exp2 domain) ----
        float pmax = max3f(sacc[0][0], sacc[0][1], sacc[0][2]);
        pmax = max3f(pmax, sacc[0][3], sacc[1][0]);
        pmax = max3f(pmax, sacc[1][1], sacc[1][2]);
        pmax = max3f(pmax, sacc[1][3], sacc[2][0]);
        pmax = max3f(pmax, sacc[2][1], sacc[2][2]);
        pmax = max3f(pmax, sacc[2][3], sacc[3][0]);
        pmax = max3f(pmax, sacc[3][1], sacc[3][2]);
        pmax = fmaxf(pmax, sacc[3][3]);
        pmax = fmaxf(pmax, __shfl_xor(pmax, 16));
        pmax = fmaxf(pmax, __shfl_xor(pmax, 32));

        if (!__all(pmax - mrow <= 64.0f)) {   // defer-max: rescale only on growth
            const float mnew  = fmaxf(mrow, pmax);
            const float alpha = exp2f((mrow - mnew) * CE);
            mrow = mnew;
            lsum *= alpha;
            #pragma unroll
            for (int r = 0; r < 4; ++r) {
                const float ar = __shfl(alpha, 4 * lg + r);
                #pragma unroll
                for (int dj = 0; dj < 4; ++dj) oacc[dj][r] *= ar;
            }
        }

        const float mc = mrow * CE;
        #pragma unroll
        for (int sj = 0; sj < 4; ++sj) {
            const float p0 = exp2f(fmaf(sacc[sj][0], CE, -mc));
            const float p1 = exp2f(fmaf(sacc[sj][1], CE, -mc));
            const float p2 = exp2f(fmaf(sacc[sj][2], CE, -mc));
            const float p3 = exp2f(fmaf(sacc[sj][3], CE, -mc));
            lsum += (p0 + p1) + (p2 + p3);
            unsigned pk0, pk1;
            asm("v_cvt_pk_bf16_f32 %0, %1, %2" : "=v"(pk0) : "v"(p0), "v"(p1));
            asm("v_cvt_pk_bf16_f32 %0, %1, %2" : "=v"(pk1) : "v"(p2), "v"(p3));
            // write keys 16sj+4lg+{0..3} of row lr: 16B-slot t = 2sj + (lg>>1)
            const int ts = 2 * sj + (lg >> 1);
            uint2* dst = (uint2*)(P_lds + w * 1024 + lr * 64 +
                                  ((ts ^ (lr & 7)) * 8) + 4 * (lg & 1));
            *dst = make_uint2(pk0, pk1);
        }

        // ---- O += P @ V ----
        __builtin_amdgcn_s_setprio(1);
        #pragma unroll
        for (int ks = 0; ks < 2; ++ks) {
            short8v pa = *(const short8v*)(P_lds + w * 1024 + lr * 64 +
                                           (((4 * ks + lg) ^ (lr & 7)) * 8));
            #pragma unroll
            for (int dj = 0; dj < 4; ++dj) {
                const int d = 16 * dj + lr;
                short8v vb = *(const short8v*)(Vc + d * 64 +
                                               (((4 * ks + lg) ^ (d & 7)) * 8));
                oacc[dj] = __builtin_amdgcn_mfma_f32_16x16x32_bf16(pa, vb, oacc[dj], 0, 0, 0);
            }
        }
        __builtin_amdgcn_s_setprio(0);

        // ---- end of tile: wait next tile's DMA, block barrier, swap ----
        asm volatile("s_waitcnt vmcnt(0)\n\ts_barrier" ::: "memory");
        cur ^= 1;
    }

    // ---- epilogue: finish row sums, normalize, store bf16 ----
    float ltot = lsum;
    ltot += __shfl_xor(ltot, 16);
    ltot += __shfl_xor(ltot, 32);
    const float linv = 1.0f / ltot;          // valid for q-row lr
    #pragma unroll
    for (int r = 0; r < 4; ++r) {
        const float inv = __shfl(linv, 4 * lg + r);
        const int q = q0 + w * 16 + 4 * lg + r;
        #pragma unroll
        for (int dj = 0; dj < 4; ++dj)
            out[((size_t)b * N + q) * D + h * 64 + 16 * dj + lr] = f2bf(oacc[dj][r] * inv);
    }
}

// ---------------------------------------------------------------------------
// prep (cvt x, transpose W) -> QKV MFMA GEMM -> V transpose -> MFMA flash attn
// -> proj MFMA GEMM (+bias, fp32 out)
// ws: x_bf 16MB | Wqkv_t 6MB | Wproj_t 2MB | qkv_bf 48MB | Vt 16MB | ao_bf 16MB
// ---------------------------------------------------------------------------
extern "C" void kernel_launch(void* const* d_in, const int* in_sizes, int n_in,
                              void* d_out, int out_size, void* d_ws, size_t ws_size,
                              hipStream_t stream) {
    const float* x     = (const float*)d_in[0];
    const float* Wqkv  = (const float*)d_in[1];
    const float* Wproj = (const float*)d_in[2];
    const float* bproj = (const float*)d_in[3];
    float* outp = (float*)d_out;

    unsigned short* x_bf    = (unsigned short*)d_ws;                 // M x D
    unsigned short* Wqkv_t  = x_bf + (size_t)M * D;                  // K3 x D
    unsigned short* Wproj_t = Wqkv_t + (size_t)K3 * D;               // D x D
    unsigned short* qkv_bf  = Wproj_t + (size_t)D * D;               // M x K3
    unsigned short* Vtp     = qkv_bf + (size_t)M * K3;               // BH x HD x N
    unsigned short* ao_bf   = Vtp + (size_t)B * H * HD * N;          // M x D

    cvt_bf16<<<(M * D / 8 + 255) / 256, 256, 0, stream>>>(x, x_bf, M * D / 8);
    transpose_w<<<dim3(K3 / 64, D / 64), 256, 0, stream>>>(Wqkv, Wqkv_t, D, K3);
    transpose_w<<<dim3(D / 64, D / 64), 256, 0, stream>>>(Wproj, Wproj_t, D, D);

    dim3 g1(K3 / 128, M / 128);
    gemm_bf16<false, unsigned short><<<g1, 256, 0, stream>>>(x_bf, Wqkv_t, qkv_bf, nullptr, M, K3, D);

    dim3 g2(N / 64, B * H);
    transposeV<<<g2, 256, 0, stream>>>(qkv_bf, Vtp);

    dim3 g3(N / 64, B * H);
    attn_mfma<<<g3, 256, 0, stream>>>(qkv_bf, Vtp, ao_bf);

    dim3 g4(D / 128, M / 128);
    gemm_bf16<true, float><<<g4, 256, 0, stream>>>(ao_bf, Wproj_t, outp, bproj, M, D, D);
}